// Round 5
// baseline (132.321 us; speedup 1.0000x reference)
//
#include <hip/hip_runtime.h>

// x: [8, 32, 32, 32, 32] fp32.  Flat = b*2^20 + i*32768 + j*1024 + k*32 + c
// W: [32, 256] row-major (o, 8 sections). Sections:
//   0:x 1:mean_i 2:mean_j 3:mean_k 4:mean_ij 5:mean_ik 6:mean_jk 7:mean_ijk
// out[b,i,j,k,o] = W0.x + B1[b,j,k,o] + B2[b,i,k,o] + A3[b,i,j,o]
//                + A12[b,k,o] + A13[b,j,o] + A23[b,i,o] + A123[b,o] + bias[o]
//
// R5: fused reduce — each block computes its S-row AND applies the weight
// GEMMs immediately, writing B/A tables directly. S1/S2/S3 never hit global.
// A12/A123 accumulate via fp32 atomics (zeroed by a 33 KB memset node).

static __device__ __forceinline__ float4 f4add(float4 a, float4 b) {
  a.x += b.x; a.y += b.y; a.z += b.z; a.w += b.w; return a;
}

__global__ __launch_bounds__(256) void fused_reduce_kernel(
    const float* __restrict__ x, const float* __restrict__ W,
    float* __restrict__ B1, float* __restrict__ B2, float* __restrict__ A3o,
    float* __restrict__ A12g, float* __restrict__ A123g,
    float* __restrict__ A13g, float* __restrict__ A23g,
    float* __restrict__ W0t) {
  __shared__ float sS[32 * 33];   // S-row [k|j][c], +1 pad (GEMM reads bank (kk+c)%32)
  __shared__ float sWa[1024];     // section seg+1 transposed [c*32+o]  (row GEMM)
  __shared__ float sWb[1024];     // seg0: W4 (A12 row GEMM)
  __shared__ float sWc[1024];     // seg0: W5 (A13) | seg1: W6 (A23)
  __shared__ float sWd[1024];     // seg0: W7 (A123)
  __shared__ float sS13[32];
  const int seg = blockIdx.x >> 8;      // 0:sum_i 1:sum_j 2:sum_k
  const int idx = blockIdx.x & 255;
  const int b = idx >> 5, a = idx & 31;
  const int t = threadIdx.x;
  const float* xb = x + ((size_t)b << 20);

  // stage transposed W sections (global reads are L2-resident after warmup)
  #pragma unroll
  for (int m = 0; m < 4; ++m) {
    const int e = t + 256 * m, c = e >> 5, o = e & 31;
    sWa[e] = W[o * 256 + (seg + 1) * 32 + c];
    if (seg == 0) {
      sWb[e] = W[o * 256 + 4 * 32 + c];
      sWc[e] = W[o * 256 + 5 * 32 + c];
      sWd[e] = W[o * 256 + 7 * 32 + c];
    } else if (seg == 1) {
      sWc[e] = W[o * 256 + 6 * 32 + c];
    }
    if (blockIdx.x == 0) W0t[e] = W[(e & 31) * 256 + (e >> 5)];  // for final
  }

  // accumulate this block's S-row; thread owns flat elements 4t..4t+3
  float4 acc = make_float4(0.f, 0.f, 0.f, 0.f);
  if (seg == 0) {            // S1[b, j=a, k, c] = sum_i
    const float* base = xb + a * 1024 + 4 * t;
    #pragma unroll
    for (int i = 0; i < 32; ++i) acc = f4add(acc, *(const float4*)(base + i * 32768));
  } else if (seg == 1) {     // S2[b, i=a, k, c] = sum_j
    const float* base = xb + a * 32768 + 4 * t;
    #pragma unroll
    for (int j = 0; j < 32; ++j) acc = f4add(acc, *(const float4*)(base + j * 1024));
  } else {                   // S3[b, i=a, j, c] = sum_k  (flat (j*32+c) = 4t)
    const float* base = xb + a * 32768 + (t >> 3) * 1024 + 4 * (t & 7);
    #pragma unroll
    for (int k = 0; k < 32; ++k) acc = f4add(acc, *(const float4*)(base + k * 32));
  }
  {  // e0=4t: e0&31 <= 28, so 4 elements stay in one padded row
    const int row = t >> 3, c0 = 4 * (t & 7);
    float* p = sS + row * 33 + c0;
    p[0] = acc.x; p[1] = acc.y; p[2] = acc.z; p[3] = acc.w;
  }
  __syncthreads();

  // row GEMM: t = kk*8 + og; thread computes outputs o = 4og..4og+3 for row kk
  const int kk = t >> 3, og = t & 7;
  float4 r1 = make_float4(0.f, 0.f, 0.f, 0.f);
  float4 r2 = make_float4(0.f, 0.f, 0.f, 0.f);
  const float4* wa4 = (const float4*)sWa;
  const float4* wb4 = (const float4*)sWb;
  #pragma unroll
  for (int c = 0; c < 32; ++c) {
    const float xv = sS[kk * 33 + c];          // broadcast x8, banks (kk+c)%32
    const float4 w = wa4[c * 8 + og];
    r1.x += xv * w.x; r1.y += xv * w.y; r1.z += xv * w.z; r1.w += xv * w.w;
    if (seg == 0) {
      const float4 w2 = wb4[c * 8 + og];
      r2.x += xv * w2.x; r2.y += xv * w2.y; r2.z += xv * w2.z; r2.w += xv * w2.w;
    }
  }
  float* dst = (seg == 0) ? B1 : (seg == 1) ? B2 : A3o;
  const size_t ofs = ((size_t)((b * 32 + a) * 32 + kk)) * 32 + 4 * og;
  *(float4*)(dst + ofs) = make_float4(r1.x * (1.f / 32.f), r1.y * (1.f / 32.f),
                                      r1.z * (1.f / 32.f), r1.w * (1.f / 32.f));
  if (seg == 0) {
    float* p = A12g + (size_t)(b * 32 + kk) * 32 + 4 * og;
    atomicAdd(p + 0, r2.x * (1.f / 1024.f));
    atomicAdd(p + 1, r2.y * (1.f / 1024.f));
    atomicAdd(p + 2, r2.z * (1.f / 1024.f));
    atomicAdd(p + 3, r2.w * (1.f / 1024.f));
  }

  if (seg <= 1) {
    // S13[b,j,c] (seg0) / S23[b,i,c] (seg1): reduce sS over its first axis
    if (t < 32) {      // lane c: at step k all 32 lanes hit distinct banks (k+c)%32
      float s = 0.f;
      #pragma unroll
      for (int k = 0; k < 32; ++k) s += sS[k * 33 + t];
      sS13[t] = s;
    }
    __syncthreads();
    if (t < 32) {
      const int o = t;
      float s5 = 0.f, s7 = 0.f;
      #pragma unroll
      for (int c = 0; c < 32; ++c) {
        const float v = sS13[c];
        s5 += sWc[c * 32 + o] * v;
        if (seg == 0) s7 += sWd[c * 32 + o] * v;
      }
      if (seg == 0) {
        A13g[(size_t)(b * 32 + a) * 32 + o] = s5 * (1.f / 1024.f);
        atomicAdd(A123g + b * 32 + o, s7 * (1.f / 32768.f));
      } else {
        A23g[(size_t)(b * 32 + a) * 32 + o] = s5 * (1.f / 1024.f);
      }
    }
  }
}

__global__ __launch_bounds__(256) void final_kernel(
    const float* __restrict__ x, const float* __restrict__ W0t,
    const float* __restrict__ B1, const float* __restrict__ B2,
    const float* __restrict__ A3o, const float* __restrict__ A12g,
    const float* __restrict__ A13g, const float* __restrict__ A23g,
    const float* __restrict__ A123g, const float* __restrict__ bias,
    float* __restrict__ out) {
  __shared__ float xs[256 * 33];
  __shared__ float wt[1024];     // W0 transposed [c*32+o]
  const int t = threadIdx.x;
  const size_t pos0 = (size_t)blockIdx.x * 256;

  const float4* xp4 = (const float4*)(x + pos0 * 32);
  #pragma unroll
  for (int m = 0; m < 8; ++m) {
    const int q = t + 256 * m;
    const float4 v = xp4[q];
    const int row = q >> 3, c0 = 4 * (q & 7);
    float* p = xs + row * 33 + c0;
    p[0] = v.x; p[1] = v.y; p[2] = v.z; p[3] = v.w;
  }
  #pragma unroll
  for (int m = 0; m < 4; ++m) wt[t + 256 * m] = W0t[t + 256 * m];
  __syncthreads();

  // thread = (rg = t>>2: 4 consecutive rows, og = t&3: 8 consecutive outs)
  const int rg = t >> 2, og = t & 3;
  const int lrow0 = 4 * rg;
  const size_t p0 = pos0 + lrow0;
  const int k0 = (int)(p0 & 31), j = (int)(p0 >> 5) & 31,
            i = (int)(p0 >> 10) & 31, b = (int)(p0 >> 15);

  float acc[4][8];
  #pragma unroll
  for (int r = 0; r < 4; ++r)
    #pragma unroll
    for (int u = 0; u < 8; ++u) acc[r][u] = 0.f;

  const float4* wt4 = (const float4*)wt;
  #pragma unroll
  for (int c = 0; c < 32; ++c) {
    const float4 w0 = wt4[c * 8 + og * 2];
    const float4 w1 = wt4[c * 8 + og * 2 + 1];
    #pragma unroll
    for (int r = 0; r < 4; ++r) {
      const float xv = xs[(lrow0 + r) * 33 + c];
      acc[r][0] += xv * w0.x; acc[r][1] += xv * w0.y;
      acc[r][2] += xv * w0.z; acc[r][3] += xv * w0.w;
      acc[r][4] += xv * w1.x; acc[r][5] += xv * w1.y;
      acc[r][6] += xv * w1.z; acc[r][7] += xv * w1.w;
    }
  }

  const int oo = og * 8;
  const float* a3   = A3o  + ((size_t)((b * 32 + i) * 32 + j)) * 32 + oo;
  const float* a13  = A13g + (size_t)(b * 32 + j) * 32 + oo;
  const float* a23  = A23g + (size_t)(b * 32 + i) * 32 + oo;
  const float* a123 = A123g + (size_t)b * 32 + oo;
  const float* bi   = bias + oo;
  float inv[8];
  #pragma unroll
  for (int u = 0; u < 8; ++u) inv[u] = a3[u] + a13[u] + a23[u] + a123[u] + bi[u];

  #pragma unroll
  for (int r = 0; r < 4; ++r) {
    const int k = k0 + r;
    const float* b1  = B1   + ((size_t)((b * 32 + j) * 32 + k)) * 32 + oo;
    const float* b2  = B2   + ((size_t)((b * 32 + i) * 32 + k)) * 32 + oo;
    const float* a12 = A12g + (size_t)(b * 32 + k) * 32 + oo;
    #pragma unroll
    for (int u = 0; u < 8; ++u) acc[r][u] += inv[u] + b1[u] + b2[u] + a12[u];
  }

  #pragma unroll
  for (int r = 0; r < 4; ++r) {
    float4* op = (float4*)(out + (p0 + r) * 32 + oo);
    op[0] = make_float4(acc[r][0], acc[r][1], acc[r][2], acc[r][3]);
    op[1] = make_float4(acc[r][4], acc[r][5], acc[r][6], acc[r][7]);
  }
}

extern "C" void kernel_launch(void* const* d_in, const int* in_sizes, int n_in,
                              void* d_out, int out_size, void* d_ws, size_t ws_size,
                              hipStream_t stream) {
  const float* x    = (const float*)d_in[0];
  const float* W    = (const float*)d_in[1];
  const float* bias = (const float*)d_in[2];
  float* out = (float*)d_out;
  float* ws  = (float*)d_ws;
  // workspace layout (floats); A12g+A123g adjacent for one memset
  float* B1    = ws;                // 262144
  float* B2    = ws + 262144;       // 262144
  float* A3o   = ws + 524288;       // 262144
  float* A12g  = ws + 786432;       // 8192
  float* A123g = ws + 794624;       // 256
  float* A13g  = ws + 794880;       // 8192
  float* A23g  = ws + 803072;       // 8192
  float* W0t   = ws + 811264;       // 1024

  // zero the atomic accumulators (ws is 0xAA-poisoned before every launch)
  hipMemsetAsync(A12g, 0, (8192 + 256) * sizeof(float), stream);
  fused_reduce_kernel<<<768, 256, 0, stream>>>(x, W, B1, B2, A3o, A12g, A123g,
                                               A13g, A23g, W0t);
  final_kernel<<<1024, 256, 0, stream>>>(x, W0t, B1, B2, A3o, A12g, A13g,
                                         A23g, A123g, bias, out);
}

// Round 6
// 111.640 us; speedup vs baseline: 1.1852x; 1.1852x over previous
//
#include <hip/hip_runtime.h>

// x: [8, 32, 32, 32, 32] fp32.  Flat = b*2^20 + i*32768 + j*1024 + k*32 + c
// W: [32, 256] row-major (o, 8 sections). Sections:
//   0:x 1:mean_i 2:mean_j 3:mean_k 4:mean_ij 5:mean_ik 6:mean_jk 7:mean_ijk
// out[b,i,j,k,o] = W0.x + B1[b,j,k,o] + B2[b,i,k,o] + A3[b,i,j,o]
//                + A12[b,k,o] + A13[b,j,o] + A23[b,i,o] + A123[b,o] + bias[o]
// R6: revert to R4 3-kernel split (R5 fusion measured -17us); merge seg1+seg2
// into one slab-streaming block (x phase-1 traffic 3x -> 2x, all contiguous).

static __device__ __forceinline__ float4 f4add(float4 a, float4 b) {
  a.x += b.x; a.y += b.y; a.z += b.z; a.w += b.w; return a;
}

__global__ __launch_bounds__(256) void reduce_kernel(
    const float* __restrict__ x, float* __restrict__ S1,
    float* __restrict__ S2, float* __restrict__ S3) {
  const int t = threadIdx.x;
  if (blockIdx.x < 256) {
    // seg0: S1[b, j=a, k, c] = sum_i x[b,i,a,k,c]; thread owns floats 4t..4t+3
    const int b = blockIdx.x >> 5, a = blockIdx.x & 31;
    const float* base = x + ((size_t)b << 20) + a * 1024 + 4 * t;
    float4 acc = make_float4(0.f, 0.f, 0.f, 0.f);
    #pragma unroll
    for (int i = 0; i < 32; ++i) acc = f4add(acc, *(const float4*)(base + i * 32768));
    ((float4*)(S1 + (size_t)(b * 32 + a) * 1024))[t] = acc;
  } else {
    // segA: block (b, i=a): stream slab x[b,a,:,:,:] once -> S2 row + S3 row
    __shared__ float sT[8 * 1028];   // 8 j-rows of [k,c] (1024) + 4 pad
    const int idx = blockIdx.x - 256;
    const int b = idx >> 5, a = idx & 31;
    const float* slab = x + ((size_t)b << 20) + a * 32768;
    float4 accS2 = make_float4(0.f, 0.f, 0.f, 0.f);
    const int jl = t >> 5, cc = t & 31;      // S3 role: (j_loc, c)
    float* s3row = S3 + (size_t)(b * 32 + a) * 1024;

    for (int jt = 0; jt < 4; ++jt) {
      // load 8 KB tile (j = 8*jt .. +7), fully coalesced float4
      const float4* src4 = (const float4*)(slab + jt * 8192);
      #pragma unroll
      for (int m = 0; m < 8; ++m) {
        const int q = t + 256 * m;           // float4 idx in tile
        const float4 v = src4[q];
        float* p = sT + (q >> 8) * 1028 + 4 * (q & 255);
        p[0] = v.x; p[1] = v.y; p[2] = v.z; p[3] = v.w;
      }
      __syncthreads();
      // S2 accumulate: thread owns (k,c) quad at 4t
      #pragma unroll
      for (int j = 0; j < 8; ++j)
        accS2 = f4add(accS2, *(const float4*)(sT + j * 1028 + 4 * t));
      // S3: thread (jl, cc) sums over k; banks (4*jl + cc + 32k)%32: 2-way free
      float s3 = 0.f;
      #pragma unroll
      for (int k = 0; k < 32; ++k) s3 += sT[jl * 1028 + k * 32 + cc];
      s3row[jt * 256 + t] = s3;              // j = 8*jt + jl, coalesced
      __syncthreads();
    }
    ((float4*)(S2 + (size_t)(b * 32 + a) * 1024))[t] = accS2;
  }
}

// Merged: blocks 0..95 = three [8192x32]x[32x32] GEMMs (B1,B2,A3, scaled 1/32);
//         blocks 96..119 = second-level pools -> A12/A13/A23/A123 tables.
__global__ __launch_bounds__(256) void mid_kernel(
    const float* __restrict__ S1, const float* __restrict__ S2,
    const float* __restrict__ S3, const float* __restrict__ W,
    float* __restrict__ B1, float* __restrict__ B2, float* __restrict__ A3o,
    float* __restrict__ A12g, float* __restrict__ A13g,
    float* __restrict__ A23g, float* __restrict__ A123g,
    float* __restrict__ W0t) {
  __shared__ float smem[9472];
  const int t = threadIdx.x;
  if (blockIdx.x < 96) {
    float* xs = smem;            // [256][33]
    float* wt = smem + 8448;     // W section seg+1 transposed [c*32+o]
    const int seg = blockIdx.x >> 5;
    const int r0 = (blockIdx.x & 31) * 256;
    const float* src = (seg == 0) ? S1 : (seg == 1) ? S2 : S3;
    float* dst = (seg == 0) ? B1 : (seg == 1) ? B2 : A3o;

    const float4* sp4 = (const float4*)(src + (size_t)r0 * 32);
    #pragma unroll
    for (int m = 0; m < 8; ++m) {
      const int q = t + 256 * m;
      const float4 v = sp4[q];
      float* p = xs + (q >> 3) * 33 + 4 * (q & 7);
      p[0] = v.x; p[1] = v.y; p[2] = v.z; p[3] = v.w;
    }
    #pragma unroll
    for (int m = 0; m < 4; ++m) {
      const int e = t + 256 * m;
      wt[e] = W[(e & 31) * 256 + (seg + 1) * 32 + (e >> 5)];
    }
    if (blockIdx.x == 0) {
      #pragma unroll
      for (int m = 0; m < 4; ++m) {
        const int e = t + 256 * m;
        W0t[e] = W[(e & 31) * 256 + (e >> 5)];   // W0t[c*32+o]
      }
    }
    __syncthreads();

    float acc[32];
    #pragma unroll
    for (int o = 0; o < 32; ++o) acc[o] = 0.f;
    const float4* wt4 = (const float4*)wt;
    #pragma unroll
    for (int c = 0; c < 32; ++c) {
      const float xv = xs[t * 33 + c];
      #pragma unroll
      for (int o4 = 0; o4 < 8; ++o4) {
        const float4 w = wt4[c * 8 + o4];
        acc[o4 * 4 + 0] += xv * w.x;
        acc[o4 * 4 + 1] += xv * w.y;
        acc[o4 * 4 + 2] += xv * w.z;
        acc[o4 * 4 + 3] += xv * w.w;
      }
    }
    __syncthreads();
    #pragma unroll
    for (int o = 0; o < 32; ++o) xs[t * 33 + o] = acc[o] * (1.f / 32.f);
    __syncthreads();
    float* op = dst + (size_t)r0 * 32;
    #pragma unroll
    for (int m = 0; m < 32; ++m) {
      const int f = t + 256 * m;
      op[f] = xs[(f >> 5) * 33 + (f & 31)];
    }
  } else {
    // pool: blk = seg*8 + b
    const int blk = blockIdx.x - 96;
    const int seg = blk >> 3, b = blk & 7;
    float* sBuf  = smem;          // [32][32] second-level sums
    float* sW    = smem + 1024;   // section 4+seg transposed [c*32+o]
    float* sW7   = smem + 2048;   // section 7 transposed
    float* sS123 = smem + 3072;   // [32]
    const int sec = 4 + seg;

    #pragma unroll
    for (int m = 0; m < 4; ++m) {
      const int e = t + 256 * m, c = e >> 5, o = e & 31;
      sW[e] = W[o * 256 + sec * 32 + c];
      if (seg == 0) sW7[e] = W[o * 256 + 7 * 32 + c];
    }
    const float* Sb = ((seg == 2) ? S2 : S1) + (size_t)b * 32768;
    #pragma unroll
    for (int m = 0; m < 4; ++m) {
      const int e = t + 256 * m, a = e >> 5, c = e & 31;
      float s = 0.f;
      if (seg == 0) {            // S12[k=a,c] = sum_j S1[b,j,a,c]
        for (int j = 0; j < 32; ++j) s += Sb[j * 1024 + a * 32 + c];
      } else {                   // S13/S23[(j|i)=a,c] = sum_k
        for (int k = 0; k < 32; ++k) s += Sb[a * 1024 + k * 32 + c];
      }
      sBuf[e] = s;
    }
    __syncthreads();
    if (seg == 0 && t < 32) {
      float s = 0.f;
      for (int k = 0; k < 32; ++k) s += sBuf[k * 32 + t];
      sS123[t] = s;
    }
    __syncthreads();
    float* Ag = (seg == 0) ? A12g : (seg == 1) ? A13g : A23g;
    #pragma unroll
    for (int m = 0; m < 4; ++m) {
      const int e = t + 256 * m, a = e >> 5, o = e & 31;
      float s = 0.f;
      #pragma unroll
      for (int c = 0; c < 32; ++c) s += sW[c * 32 + o] * sBuf[a * 32 + c];
      Ag[b * 1024 + e] = s * (1.f / 1024.f);
    }
    if (seg == 0 && t < 32) {
      float s = 0.f;
      #pragma unroll
      for (int c = 0; c < 32; ++c) s += sW7[c * 32 + t] * sS123[c];
      A123g[b * 32 + t] = s * (1.f / 32768.f);
    }
  }
}

__global__ __launch_bounds__(256) void final_kernel(
    const float* __restrict__ x, const float* __restrict__ W0t,
    const float* __restrict__ B1, const float* __restrict__ B2,
    const float* __restrict__ A3o, const float* __restrict__ A12g,
    const float* __restrict__ A13g, const float* __restrict__ A23g,
    const float* __restrict__ A123g, const float* __restrict__ bias,
    float* __restrict__ out) {
  __shared__ float xs[256 * 33];
  __shared__ float wt[1024];     // W0 transposed [c*32+o]
  const int t = threadIdx.x;
  const size_t pos0 = (size_t)blockIdx.x * 256;

  const float4* xp4 = (const float4*)(x + pos0 * 32);
  #pragma unroll
  for (int m = 0; m < 8; ++m) {
    const int q = t + 256 * m;
    const float4 v = xp4[q];
    float* p = xs + (q >> 3) * 33 + 4 * (q & 7);
    p[0] = v.x; p[1] = v.y; p[2] = v.z; p[3] = v.w;
  }
  #pragma unroll
  for (int m = 0; m < 4; ++m) wt[t + 256 * m] = W0t[t + 256 * m];
  __syncthreads();

  // thread = (rg = t>>2: 4 consecutive rows, og = t&3: 8 consecutive outs)
  const int rg = t >> 2, og = t & 3;
  const int lrow0 = 4 * rg;
  const size_t p0 = pos0 + lrow0;
  const int k0 = (int)(p0 & 31), j = (int)(p0 >> 5) & 31,
            i = (int)(p0 >> 10) & 31, b = (int)(p0 >> 15);

  float acc[4][8];
  #pragma unroll
  for (int r = 0; r < 4; ++r)
    #pragma unroll
    for (int u = 0; u < 8; ++u) acc[r][u] = 0.f;

  const float4* wt4 = (const float4*)wt;
  #pragma unroll
  for (int c = 0; c < 32; ++c) {
    const float4 w0 = wt4[c * 8 + og * 2];
    const float4 w1 = wt4[c * 8 + og * 2 + 1];
    #pragma unroll
    for (int r = 0; r < 4; ++r) {
      const float xv = xs[(lrow0 + r) * 33 + c];
      acc[r][0] += xv * w0.x; acc[r][1] += xv * w0.y;
      acc[r][2] += xv * w0.z; acc[r][3] += xv * w0.w;
      acc[r][4] += xv * w1.x; acc[r][5] += xv * w1.y;
      acc[r][6] += xv * w1.z; acc[r][7] += xv * w1.w;
    }
  }

  const int oo = og * 8;
  const float* a3   = A3o  + ((size_t)((b * 32 + i) * 32 + j)) * 32 + oo;
  const float* a13  = A13g + (size_t)(b * 32 + j) * 32 + oo;
  const float* a23  = A23g + (size_t)(b * 32 + i) * 32 + oo;
  const float* a123 = A123g + (size_t)b * 32 + oo;
  const float* bi   = bias + oo;
  float inv[8];
  #pragma unroll
  for (int u = 0; u < 8; ++u) inv[u] = a3[u] + a13[u] + a23[u] + a123[u] + bi[u];

  #pragma unroll
  for (int r = 0; r < 4; ++r) {
    const int k = k0 + r;
    const float* b1  = B1   + ((size_t)((b * 32 + j) * 32 + k)) * 32 + oo;
    const float* b2  = B2   + ((size_t)((b * 32 + i) * 32 + k)) * 32 + oo;
    const float* a12 = A12g + (size_t)(b * 32 + k) * 32 + oo;
    #pragma unroll
    for (int u = 0; u < 8; ++u) acc[r][u] += inv[u] + b1[u] + b2[u] + a12[u];
  }

  #pragma unroll
  for (int r = 0; r < 4; ++r) {
    float4* op = (float4*)(out + (p0 + r) * 32 + oo);
    op[0] = make_float4(acc[r][0], acc[r][1], acc[r][2], acc[r][3]);
    op[1] = make_float4(acc[r][4], acc[r][5], acc[r][6], acc[r][7]);
  }
}

extern "C" void kernel_launch(void* const* d_in, const int* in_sizes, int n_in,
                              void* d_out, int out_size, void* d_ws, size_t ws_size,
                              hipStream_t stream) {
  const float* x    = (const float*)d_in[0];
  const float* W    = (const float*)d_in[1];
  const float* bias = (const float*)d_in[2];
  float* out = (float*)d_out;
  float* ws  = (float*)d_ws;
  float* S1    = ws;                // 262144
  float* S2    = ws + 262144;
  float* S3    = ws + 524288;
  float* B1    = ws + 786432;
  float* B2    = ws + 1048576;
  float* A3o   = ws + 1310720;
  float* W0t   = ws + 1572864;      // 1024
  float* A12g  = ws + 1573888;      // 8192
  float* A13g  = ws + 1582080;      // 8192
  float* A23g  = ws + 1590272;      // 8192
  float* A123g = ws + 1598464;      // 256

  reduce_kernel<<<512, 256, 0, stream>>>(x, S1, S2, S3);
  mid_kernel<<<120, 256, 0, stream>>>(S1, S2, S3, W, B1, B2, A3o,
                                      A12g, A13g, A23g, A123g, W0t);
  final_kernel<<<1024, 256, 0, stream>>>(x, W0t, B1, B2, A3o, A12g, A13g,
                                         A23g, A123g, bias, out);
}